// Round 1
// baseline (1425.369 us; speedup 1.0000x reference)
//
#include <hip/hip_runtime.h>
#include <math.h>

#define SEQ    2048
#define BATCH  2
#define DMODEL 1024
#define NHEADS 16
#define DK     64
#define MROWS  (SEQ*BATCH)   // 4096

// ---------------------------------------------------------------------------
// Kernel 1: QKV projection.
// C[m][n] = A_third[m][:] . in_proj_w[n][:] + in_proj_b[n]
// m = s*B + b (input rows of q/k/v, which are (S,B,D) row-major -> row m has
// stride DMODEL). n in [0,3072): n<1024 -> q-proj, <2048 -> k-proj, else v.
// Output scattered to head-major (b*H+h, s, d) layout for attention.
// 64x64 tile, BK=16, 256 threads, 4x4 microtile per thread.
// ---------------------------------------------------------------------------
__global__ __launch_bounds__(256) void qkv_proj_kernel(
    const float* __restrict__ q, const float* __restrict__ k, const float* __restrict__ v,
    const float* __restrict__ w, const float* __restrict__ bias,
    float* __restrict__ qh, float* __restrict__ kh, float* __restrict__ vh)
{
    __shared__ float As[16][65];   // [k][m], +1 pad
    __shared__ float Ws[16][65];   // [k][n]
    const int t  = threadIdx.x;
    const int n0 = blockIdx.x * 64;       // 0..3071, tile stays inside one third
    const int m0 = blockIdx.y * 64;
    const int which = n0 >> 10;           // 0=q,1=k,2=v (uniform per block)
    const float* A = (which == 0) ? q : (which == 1) ? k : v;
    float* Cdst    = (which == 0) ? qh : (which == 1) ? kh : vh;

    const int tx = t & 15, ty = t >> 4;
    const int lrow = t >> 2;              // 0..63
    const int lk4  = (t & 3) << 2;        // 0,4,8,12

    float acc[4][4] = {{0.f}};

    for (int kt = 0; kt < DMODEL; kt += 16) {
        float4 av = *(const float4*)(A + (size_t)(m0 + lrow) * DMODEL + kt + lk4);
        float4 wv = *(const float4*)(w + (size_t)(n0 + lrow) * DMODEL + kt + lk4);
        __syncthreads();
        As[lk4+0][lrow] = av.x; As[lk4+1][lrow] = av.y;
        As[lk4+2][lrow] = av.z; As[lk4+3][lrow] = av.w;
        Ws[lk4+0][lrow] = wv.x; Ws[lk4+1][lrow] = wv.y;
        Ws[lk4+2][lrow] = wv.z; Ws[lk4+3][lrow] = wv.w;
        __syncthreads();
        #pragma unroll
        for (int kk = 0; kk < 16; ++kk) {
            float a[4], b[4];
            #pragma unroll
            for (int i = 0; i < 4; ++i) a[i] = As[kk][ty*4+i];
            #pragma unroll
            for (int j = 0; j < 4; ++j) b[j] = Ws[kk][tx*4+j];
            #pragma unroll
            for (int i = 0; i < 4; ++i)
                #pragma unroll
                for (int j = 0; j < 4; ++j)
                    acc[i][j] += a[i]*b[j];
        }
    }

    #pragma unroll
    for (int i = 0; i < 4; ++i) {
        const int m = m0 + ty*4 + i;
        const int s = m >> 1;             // BATCH==2
        const int b = m & 1;
        #pragma unroll
        for (int j = 0; j < 4; ++j) {
            const int n   = n0 + tx*4 + j;
            const int rem = n & 1023;
            const int h   = rem >> 6;
            const int d   = rem & 63;
            Cdst[(((size_t)(b*NHEADS + h)) * SEQ + s) * DK + d] = acc[i][j] + bias[n];
        }
    }
}

// ---------------------------------------------------------------------------
// Kernel 2: flash attention (online softmax, no S x S materialization).
// One block per (head bh, 64-row Q tile). 256 threads. K/V in 64x64 LDS tiles.
// Writes O directly into (S*B, D) row-major layout for the out-projection.
// ---------------------------------------------------------------------------
__global__ __launch_bounds__(256) void attn_kernel(
    const float* __restrict__ qh, const float* __restrict__ kh,
    const float* __restrict__ vh, float* __restrict__ attn)
{
    __shared__ float Qs[64][65];
    __shared__ float Ks[64][65];
    __shared__ float Vs[64][65];
    __shared__ float Ps[64][65];
    __shared__ float red[64][17];
    __shared__ float m_s[64], l_s[64], alpha_s[64];

    const int t  = threadIdx.x;
    const int qt = blockIdx.x;            // 0..31
    const int bh = blockIdx.y;            // 0..31  (= b*NHEADS + h)
    const int tx = t & 15, ty = t >> 4;

    const float* Qbase = qh + ((size_t)bh * SEQ + qt * 64) * DK;
    const float* Kbase = kh + (size_t)bh * SEQ * DK;
    const float* Vbase = vh + (size_t)bh * SEQ * DK;

    // load Q tile, pre-scaled by 1/sqrt(dk)
    #pragma unroll
    for (int j = 0; j < 4; ++j) {
        int fi  = j*256 + t;              // float4 index 0..1023
        int row = fi >> 4;
        int c0  = (fi & 15) << 2;
        float4 vq = *(const float4*)(Qbase + row*DK + c0);
        Qs[row][c0+0] = vq.x * 0.125f; Qs[row][c0+1] = vq.y * 0.125f;
        Qs[row][c0+2] = vq.z * 0.125f; Qs[row][c0+3] = vq.w * 0.125f;
    }
    if (t < 64) { m_s[t] = -INFINITY; l_s[t] = 0.f; }

    float O[4][4] = {{0.f}};

    for (int ktile = 0; ktile < SEQ/64; ++ktile) {
        __syncthreads();                  // prev iter done reading Ks/Vs
        const float* Kt = Kbase + (size_t)ktile * 64 * DK;
        const float* Vt = Vbase + (size_t)ktile * 64 * DK;
        #pragma unroll
        for (int j = 0; j < 4; ++j) {
            int fi  = j*256 + t;
            int row = fi >> 4;
            int c0  = (fi & 15) << 2;
            float4 kv = *(const float4*)(Kt + row*DK + c0);
            float4 vv = *(const float4*)(Vt + row*DK + c0);
            Ks[row][c0+0] = kv.x; Ks[row][c0+1] = kv.y;
            Ks[row][c0+2] = kv.z; Ks[row][c0+3] = kv.w;
            Vs[row][c0+0] = vv.x; Vs[row][c0+1] = vv.y;
            Vs[row][c0+2] = vv.z; Vs[row][c0+3] = vv.w;
        }
        __syncthreads();

        // Sc[i][j] = Q[ty*4+i][:] . K[tx*4+j][:]
        float Sc[4][4] = {{0.f}};
        for (int d = 0; d < 64; ++d) {
            float a[4], b[4];
            #pragma unroll
            for (int i = 0; i < 4; ++i) a[i] = Qs[ty*4+i][d];
            #pragma unroll
            for (int j = 0; j < 4; ++j) b[j] = Ks[tx*4+j][d];
            #pragma unroll
            for (int i = 0; i < 4; ++i)
                #pragma unroll
                for (int j = 0; j < 4; ++j)
                    Sc[i][j] += a[i]*b[j];
        }

        // per-thread row max -> LDS reduce across the 16 tx columns
        #pragma unroll
        for (int i = 0; i < 4; ++i) {
            float lm = Sc[i][0];
            #pragma unroll
            for (int j = 1; j < 4; ++j) lm = fmaxf(lm, Sc[i][j]);
            red[ty*4+i][tx] = lm;
        }
        __syncthreads();
        if (t < 64) {
            float mx = red[t][0];
            #pragma unroll
            for (int x = 1; x < 16; ++x) mx = fmaxf(mx, red[t][x]);
            float mo = m_s[t];
            float mn = fmaxf(mo, mx);
            m_s[t] = mn;
            alpha_s[t] = (mo == -INFINITY) ? 0.f : __expf(mo - mn);
        }
        __syncthreads();

        // P = exp(S - m_new); partial row sums; rescale O
        #pragma unroll
        for (int i = 0; i < 4; ++i) {
            const int row = ty*4 + i;
            const float mrow = m_s[row];
            float ssum = 0.f;
            #pragma unroll
            for (int j = 0; j < 4; ++j) {
                float p = __expf(Sc[i][j] - mrow);
                Ps[row][tx*4+j] = p;
                ssum += p;
            }
            red[row][tx] = ssum;
            const float al = alpha_s[row];
            #pragma unroll
            for (int j = 0; j < 4; ++j) O[i][j] *= al;
        }
        __syncthreads();
        if (t < 64) {
            float sum = 0.f;
            #pragma unroll
            for (int x = 0; x < 16; ++x) sum += red[t][x];
            l_s[t] = l_s[t]*alpha_s[t] + sum;
        }

        // O[i][j] += sum_c P[ty*4+i][c] * V[c][tx*4+j]
        for (int c = 0; c < 64; ++c) {
            float a[4], b[4];
            #pragma unroll
            for (int i = 0; i < 4; ++i) a[i] = Ps[ty*4+i][c];
            #pragma unroll
            for (int j = 0; j < 4; ++j) b[j] = Vs[c][tx*4+j];
            #pragma unroll
            for (int i = 0; i < 4; ++i)
                #pragma unroll
                for (int j = 0; j < 4; ++j)
                    O[i][j] += a[i]*b[j];
        }
    }
    __syncthreads();

    // normalize and store to (S*B, D) layout: row = s*B + b, col = h*64 + d
    const int b_ = bh / NHEADS;
    const int h_ = bh % NHEADS;
    #pragma unroll
    for (int i = 0; i < 4; ++i) {
        const int row = ty*4 + i;
        const float inv = 1.f / l_s[row];
        const int s_ = qt*64 + row;
        #pragma unroll
        for (int j = 0; j < 4; ++j) {
            const int d = tx*4 + j;
            attn[((size_t)(s_*BATCH + b_)) * DMODEL + h_*DK + d] = O[i][j] * inv;
        }
    }
}

// ---------------------------------------------------------------------------
// Kernel 3: out projection. out[m][n] = A[m][:] . out_proj_w[n][:] + b[n]
// ---------------------------------------------------------------------------
__global__ __launch_bounds__(256) void out_proj_kernel(
    const float* __restrict__ A, const float* __restrict__ w,
    const float* __restrict__ bias, float* __restrict__ out)
{
    __shared__ float As[16][65];
    __shared__ float Ws[16][65];
    const int t  = threadIdx.x;
    const int n0 = blockIdx.x * 64;
    const int m0 = blockIdx.y * 64;
    const int tx = t & 15, ty = t >> 4;
    const int lrow = t >> 2;
    const int lk4  = (t & 3) << 2;

    float acc[4][4] = {{0.f}};

    for (int kt = 0; kt < DMODEL; kt += 16) {
        float4 av = *(const float4*)(A + (size_t)(m0 + lrow) * DMODEL + kt + lk4);
        float4 wv = *(const float4*)(w + (size_t)(n0 + lrow) * DMODEL + kt + lk4);
        __syncthreads();
        As[lk4+0][lrow] = av.x; As[lk4+1][lrow] = av.y;
        As[lk4+2][lrow] = av.z; As[lk4+3][lrow] = av.w;
        Ws[lk4+0][lrow] = wv.x; Ws[lk4+1][lrow] = wv.y;
        Ws[lk4+2][lrow] = wv.z; Ws[lk4+3][lrow] = wv.w;
        __syncthreads();
        #pragma unroll
        for (int kk = 0; kk < 16; ++kk) {
            float a[4], b[4];
            #pragma unroll
            for (int i = 0; i < 4; ++i) a[i] = As[kk][ty*4+i];
            #pragma unroll
            for (int j = 0; j < 4; ++j) b[j] = Ws[kk][tx*4+j];
            #pragma unroll
            for (int i = 0; i < 4; ++i)
                #pragma unroll
                for (int j = 0; j < 4; ++j)
                    acc[i][j] += a[i]*b[j];
        }
    }

    #pragma unroll
    for (int i = 0; i < 4; ++i) {
        const int m = m0 + ty*4 + i;
        #pragma unroll
        for (int j = 0; j < 4; ++j) {
            const int n = n0 + tx*4 + j;
            out[(size_t)m * DMODEL + n] = acc[i][j] + bias[n];
        }
    }
}

// ---------------------------------------------------------------------------
extern "C" void kernel_launch(void* const* d_in, const int* in_sizes, int n_in,
                              void* d_out, int out_size, void* d_ws, size_t ws_size,
                              hipStream_t stream) {
    const float* q     = (const float*)d_in[0];
    const float* k     = (const float*)d_in[1];
    const float* v     = (const float*)d_in[2];
    const float* w_in  = (const float*)d_in[3];
    const float* b_in  = (const float*)d_in[4];
    const float* w_out = (const float*)d_in[5];
    const float* b_out = (const float*)d_in[6];
    float* out = (float*)d_out;

    // workspace layout (floats): qh | kh | vh | attn, each 32*2048*64 = 4194304
    float* ws   = (float*)d_ws;
    float* qh   = ws;
    float* khw  = ws + 4194304;
    float* vhw  = ws + 8388608;
    float* attn = ws + 12582912;   // total 67.1 MB

    qkv_proj_kernel<<<dim3(48, 64), 256, 0, stream>>>(q, k, v, w_in, b_in, qh, khw, vhw);
    attn_kernel<<<dim3(32, 32), 256, 0, stream>>>(qh, khw, vhw, attn);
    out_proj_kernel<<<dim3(16, 64), 256, 0, stream>>>(attn, w_out, b_out, out);
}

// Round 2
// 322.098 us; speedup vs baseline: 4.4253x; 4.4253x over previous
//
#include <hip/hip_runtime.h>
#include <math.h>

#define SEQ    2048
#define BATCH  2
#define DMODEL 1024
#define NHEADS 16
#define DK     64

typedef __attribute__((ext_vector_type(8))) short  bf16x8;
typedef __attribute__((ext_vector_type(4))) float  f32x4;
typedef __attribute__((ext_vector_type(8))) unsigned short u16x8;

// async global->LDS, 16B per lane. LDS dest must be uniform_base + lane*16.
#define GLD16(gp, lp) __builtin_amdgcn_global_load_lds(                      \
    (__attribute__((address_space(1))) void*)(gp),                            \
    (__attribute__((address_space(3))) void*)(lp), 16, 0, 0)

__device__ inline unsigned short f2bf(float f) {
    unsigned int u = __float_as_uint(f);
    u += 0x7fffu + ((u >> 16) & 1u);   // round-to-nearest-even
    return (unsigned short)(u >> 16);
}

// workspace layout (ushort units)
#define WS_QB   0u
#define WS_KB   4194304u
#define WS_VB   8388608u
#define WS_WIB  12582912u
#define WS_WOB  15728640u
#define WS_QH   16777216u
#define WS_KH   20971520u
#define WS_VT   25165824u
#define WS_ATT  29360128u
// total 33554432 ushorts = 64 MB

// ---------------------------------------------------------------------------
// Cast all f32 inputs to bf16 in workspace. 8 floats / thread.
// ---------------------------------------------------------------------------
__global__ __launch_bounds__(256) void cast_all_kernel(
    const float* __restrict__ q, const float* __restrict__ k,
    const float* __restrict__ v, const float* __restrict__ w_in,
    const float* __restrict__ w_out, unsigned short* __restrict__ ws)
{
    const int gid = blockIdx.x * 256 + threadIdx.x;   // 0..2097151
    const float* src; unsigned short* dst;
    if (gid < 524288)       { int g = gid;           src = q     + (size_t)g*8; dst = ws + WS_QB  + (size_t)g*8; }
    else if (gid < 1048576) { int g = gid - 524288;  src = k     + (size_t)g*8; dst = ws + WS_KB  + (size_t)g*8; }
    else if (gid < 1572864) { int g = gid - 1048576; src = v     + (size_t)g*8; dst = ws + WS_VB  + (size_t)g*8; }
    else if (gid < 1966080) { int g = gid - 1572864; src = w_in  + (size_t)g*8; dst = ws + WS_WIB + (size_t)g*8; }
    else                    { int g = gid - 1966080; src = w_out + (size_t)g*8; dst = ws + WS_WOB + (size_t)g*8; }
    float4 a = *(const float4*)src;
    float4 b = *(const float4*)(src + 4);
    u16x8 o;
    o[0]=f2bf(a.x); o[1]=f2bf(a.y); o[2]=f2bf(a.z); o[3]=f2bf(a.w);
    o[4]=f2bf(b.x); o[5]=f2bf(b.y); o[6]=f2bf(b.z); o[7]=f2bf(b.w);
    *(u16x8*)dst = o;
}

// ---------------------------------------------------------------------------
// QKV projection GEMM-BT (MFMA): C[m][n] = sum_k A[m][k]*W[n][k] + bias[n]
// A = qb/kb/vb (4096 x 1024 bf16), W = w_in_b (3072 x 1024 bf16).
// 128x128 tile, BK=32, 4 waves each 64x64 (4x4 MFMA tiles of 16x16x32).
// Epilogue scatters: Q,K -> head-major (bh, s, d); V -> transposed (bh, d, s).
// ---------------------------------------------------------------------------
__global__ __launch_bounds__(256) void qkv_gemm_kernel(
    const unsigned short* __restrict__ ws_in, const float* __restrict__ bias,
    unsigned short* __restrict__ ws_out)
{
    __shared__ unsigned short As[128*32];   // 8 KB, row-major rows of 32
    __shared__ unsigned short Bs[128*32];   // 8 KB

    const int t    = threadIdx.x;
    const int lane = t & 63;
    const int w    = t >> 6;
    const int lrow = lane & 15;
    const int quad = lane >> 4;
    const int wm   = (w >> 1) * 64;
    const int wn   = (w & 1) * 64;

    const int n0    = blockIdx.x * 128;    // 0..2944
    const int m0    = blockIdx.y * 128;
    const int which = n0 >> 10;            // 0=q,1=k,2=v (tile within one third)

    const unsigned short* A = ws_in + WS_QB + (size_t)which * 4194304u;
    const unsigned short* B = ws_in + WS_WIB;

    // staging pointers: chunk c (16B) -> row c>>2, colchunk c&3
    const unsigned short* gA0 = A + (size_t)(m0 + (t >> 2)) * 1024 + (t & 3) * 8;
    const unsigned short* gA1 = A + (size_t)(m0 + 64 + (t >> 2)) * 1024 + (t & 3) * 8;
    const unsigned short* gB0 = B + (size_t)(n0 + (t >> 2)) * 1024 + (t & 3) * 8;
    const unsigned short* gB1 = B + (size_t)(n0 + 64 + (t >> 2)) * 1024 + (t & 3) * 8;

    f32x4 acc[4][4] = {};

    #pragma unroll 1
    for (int kt = 0; kt < 1024; kt += 32) {
        __syncthreads();
        GLD16(gA0, As + (size_t)t * 8);
        GLD16(gA1, As + (size_t)(t + 256) * 8);
        GLD16(gB0, Bs + (size_t)t * 8);
        GLD16(gB1, Bs + (size_t)(t + 256) * 8);
        gA0 += 32; gA1 += 32; gB0 += 32; gB1 += 32;
        __syncthreads();

        bf16x8 af[4], bf[4];
        #pragma unroll
        for (int mt = 0; mt < 4; ++mt)
            af[mt] = *(const bf16x8*)(As + (wm + mt*16 + lrow) * 32 + quad * 8);
        #pragma unroll
        for (int nt = 0; nt < 4; ++nt)
            bf[nt] = *(const bf16x8*)(Bs + (wn + nt*16 + lrow) * 32 + quad * 8);
        #pragma unroll
        for (int mt = 0; mt < 4; ++mt)
            #pragma unroll
            for (int nt = 0; nt < 4; ++nt)
                acc[mt][nt] = __builtin_amdgcn_mfma_f32_16x16x32_bf16(
                    af[mt], bf[nt], acc[mt][nt], 0, 0, 0);
    }

    // epilogue: C layout col = lane&15, row = quad*4 + r
    unsigned short* dstQK = ws_out + WS_QH + (size_t)which * 4194304u;  // valid for which<2
    unsigned short* dstV  = ws_out + WS_VT;
    #pragma unroll
    for (int nt = 0; nt < 4; ++nt) {
        const int n = n0 + wn + nt*16 + lrow;
        const float bn = bias[n];
        const int h = (n & 1023) >> 6;
        const int d = n & 63;
        #pragma unroll
        for (int mt = 0; mt < 4; ++mt) {
            #pragma unroll
            for (int r = 0; r < 4; ++r) {
                const int m = m0 + wm + mt*16 + quad*4 + r;
                const int s = m >> 1, b = m & 1;
                const unsigned short val = f2bf(acc[mt][nt][r] + bn);
                if (which < 2)
                    dstQK[((size_t)((b<<4) + h) * 2048 + s) * 64 + d] = val;
                else
                    dstV[((size_t)((b<<4) + h) * 64 + d) * 2048 + s] = val;
            }
        }
    }
}

// ---------------------------------------------------------------------------
// Flash attention (MFMA, online softmax). Block = (qtile of 128 rows, bh).
// 4 waves; wave w owns Q rows [w*32, w*32+32). K/V tiles of 64 keys.
// ---------------------------------------------------------------------------
__global__ __launch_bounds__(256) void attn_mfma_kernel(
    const unsigned short* __restrict__ qh, const unsigned short* __restrict__ kh,
    const unsigned short* __restrict__ vt, unsigned short* __restrict__ attn)
{
    __shared__ unsigned short Qs[128*64];   // 16 KB, row-major rows of 64
    __shared__ unsigned short Ks[64*64];    // 8 KB
    __shared__ unsigned short Vts[64*64];   // 8 KB  (rows = d, cols = key)
    __shared__ unsigned short Ps[128*72];   // 18 KB (row stride 72 = pad +8)

    const int t    = threadIdx.x;
    const int lane = t & 63;
    const int w    = t >> 6;
    const int lrow = lane & 15;
    const int quad = lane >> 4;

    const int qt = blockIdx.x;   // 0..15
    const int bh = blockIdx.y;   // 0..31

    const unsigned short* Qg = qh + ((size_t)bh * 2048 + qt * 128) * 64;
    const unsigned short* Kb = kh + (size_t)bh * 2048 * 64;
    const unsigned short* Vb = vt + (size_t)bh * 64 * 2048;

    // stage Q tile (1024 chunks of 16B, 4 per thread); rows contiguous
    #pragma unroll
    for (int i = 0; i < 4; ++i) {
        const int c = i * 256 + t;
        GLD16(Qg + (size_t)c * 8, Qs + (size_t)c * 8);
    }

    f32x4 O[2][4] = {};
    float m_i[2][4], l_i[2][4];
    #pragma unroll
    for (int mt = 0; mt < 2; ++mt)
        #pragma unroll
        for (int r = 0; r < 4; ++r) { m_i[mt][r] = -INFINITY; l_i[mt][r] = 0.f; }

    #pragma unroll 1
    for (int ktile = 0; ktile < 32; ++ktile) {
        __syncthreads();   // Ks/Vts free; also drains Q loads on first iter
        const unsigned short* Kg = Kb + (size_t)ktile * 64 * 64;
        const unsigned short* Vg = Vb + (size_t)ktile * 64;
        GLD16(Kg + (size_t)t * 8, Ks + (size_t)t * 8);
        GLD16(Kg + (size_t)(t + 256) * 8, Ks + (size_t)(t + 256) * 8);
        {   // V^T tile: chunk c -> row d=c>>3, colchunk c&7; global row stride 2048
            const int c0 = t, c1 = t + 256;
            GLD16(Vg + (size_t)(c0 >> 3) * 2048 + (c0 & 7) * 8, Vts + (size_t)c0 * 8);
            GLD16(Vg + (size_t)(c1 >> 3) * 2048 + (c1 & 7) * 8, Vts + (size_t)c1 * 8);
        }
        __syncthreads();

        // S = Q . K^T  (dk=64 -> 2 MFMA k-steps)
        f32x4 S[2][4] = {};
        #pragma unroll
        for (int kk = 0; kk < 2; ++kk) {
            bf16x8 aq[2], bk[4];
            #pragma unroll
            for (int mt = 0; mt < 2; ++mt)
                aq[mt] = *(const bf16x8*)(Qs + (w*32 + mt*16 + lrow) * 64 + kk*32 + quad*8);
            #pragma unroll
            for (int nt = 0; nt < 4; ++nt)
                bk[nt] = *(const bf16x8*)(Ks + (nt*16 + lrow) * 64 + kk*32 + quad*8);
            #pragma unroll
            for (int mt = 0; mt < 2; ++mt)
                #pragma unroll
                for (int nt = 0; nt < 4; ++nt)
                    S[mt][nt] = __builtin_amdgcn_mfma_f32_16x16x32_bf16(
                        aq[mt], bk[nt], S[mt][nt], 0, 0, 0);
        }
        #pragma unroll
        for (int mt = 0; mt < 2; ++mt)
            #pragma unroll
            for (int nt = 0; nt < 4; ++nt)
                S[mt][nt] *= 0.125f;   // 1/sqrt(dk)

        // online softmax. Row (mt, r) lives in the 16 lanes of this quad.
        #pragma unroll
        for (int mt = 0; mt < 2; ++mt) {
            #pragma unroll
            for (int r = 0; r < 4; ++r) {
                float mx = fmaxf(fmaxf(S[0+mt*0][0][r], S[mt][1][r]),
                                 fmaxf(S[mt][2][r], S[mt][3][r]));
                mx = fmaxf(mx, S[mt][0][r]);
                #pragma unroll
                for (int off = 1; off <= 8; off <<= 1)
                    mx = fmaxf(mx, __shfl_xor(mx, off, 64));
                const float mo = m_i[mt][r];
                const float mn = fmaxf(mo, mx);
                const float al = __expf(mo - mn);
                m_i[mt][r] = mn;
                float rsum = 0.f;
                const int prow = (w*32 + mt*16 + quad*4 + r) * 72;
                #pragma unroll
                for (int nt = 0; nt < 4; ++nt) {
                    const float p = __expf(S[mt][nt][r] - mn);
                    Ps[prow + nt*16 + lrow] = f2bf(p);
                    rsum += p;
                }
                #pragma unroll
                for (int off = 1; off <= 8; off <<= 1)
                    rsum += __shfl_xor(rsum, off, 64);
                l_i[mt][r] = l_i[mt][r] * al + rsum;
                #pragma unroll
                for (int dt = 0; dt < 4; ++dt)
                    O[mt][dt][r] *= al;
            }
        }

        // O += P . V  (P rows are wave-private; DS pipe is in-order per wave)
        #pragma unroll
        for (int kk = 0; kk < 2; ++kk) {
            bf16x8 ap[2], bv[4];
            #pragma unroll
            for (int mt = 0; mt < 2; ++mt)
                ap[mt] = *(const bf16x8*)(Ps + (w*32 + mt*16 + lrow) * 72 + kk*32 + quad*8);
            #pragma unroll
            for (int dt = 0; dt < 4; ++dt)
                bv[dt] = *(const bf16x8*)(Vts + (dt*16 + lrow) * 64 + kk*32 + quad*8);
            #pragma unroll
            for (int mt = 0; mt < 2; ++mt)
                #pragma unroll
                for (int dt = 0; dt < 4; ++dt)
                    O[mt][dt] = __builtin_amdgcn_mfma_f32_16x16x32_bf16(
                        ap[mt], bv[dt], O[mt][dt], 0, 0, 0);
        }
    }

    // epilogue: attn row = s*B + b, col = h*64 + d (bf16)
    const int b_ = bh >> 4, h_ = bh & 15;
    #pragma unroll
    for (int mt = 0; mt < 2; ++mt) {
        #pragma unroll
        for (int r = 0; r < 4; ++r) {
            const float inv = 1.f / l_i[mt][r];
            const int s_ = qt*128 + w*32 + mt*16 + quad*4 + r;
            #pragma unroll
            for (int dt = 0; dt < 4; ++dt) {
                const int d = dt*16 + lrow;
                attn[((size_t)(s_*2 + b_)) * 1024 + h_*64 + d] =
                    f2bf(O[mt][dt][r] * inv);
            }
        }
    }
}

// ---------------------------------------------------------------------------
// Out projection GEMM-BT (MFMA): out[m][n] = sum_k attn[m][k]*W[n][k] + b[n]
// M=4096, N=1024, K=1024; f32 output.
// ---------------------------------------------------------------------------
__global__ __launch_bounds__(256) void out_gemm_kernel(
    const unsigned short* __restrict__ A, const unsigned short* __restrict__ B,
    const float* __restrict__ bias, float* __restrict__ out)
{
    __shared__ unsigned short As[128*32];
    __shared__ unsigned short Bs[128*32];

    const int t    = threadIdx.x;
    const int lane = t & 63;
    const int w    = t >> 6;
    const int lrow = lane & 15;
    const int quad = lane >> 4;
    const int wm   = (w >> 1) * 64;
    const int wn   = (w & 1) * 64;

    const int n0 = blockIdx.x * 128;
    const int m0 = blockIdx.y * 128;

    const unsigned short* gA0 = A + (size_t)(m0 + (t >> 2)) * 1024 + (t & 3) * 8;
    const unsigned short* gA1 = A + (size_t)(m0 + 64 + (t >> 2)) * 1024 + (t & 3) * 8;
    const unsigned short* gB0 = B + (size_t)(n0 + (t >> 2)) * 1024 + (t & 3) * 8;
    const unsigned short* gB1 = B + (size_t)(n0 + 64 + (t >> 2)) * 1024 + (t & 3) * 8;

    f32x4 acc[4][4] = {};

    #pragma unroll 1
    for (int kt = 0; kt < 1024; kt += 32) {
        __syncthreads();
        GLD16(gA0, As + (size_t)t * 8);
        GLD16(gA1, As + (size_t)(t + 256) * 8);
        GLD16(gB0, Bs + (size_t)t * 8);
        GLD16(gB1, Bs + (size_t)(t + 256) * 8);
        gA0 += 32; gA1 += 32; gB0 += 32; gB1 += 32;
        __syncthreads();

        bf16x8 af[4], bf[4];
        #pragma unroll
        for (int mt = 0; mt < 4; ++mt)
            af[mt] = *(const bf16x8*)(As + (wm + mt*16 + lrow) * 32 + quad * 8);
        #pragma unroll
        for (int nt = 0; nt < 4; ++nt)
            bf[nt] = *(const bf16x8*)(Bs + (wn + nt*16 + lrow) * 32 + quad * 8);
        #pragma unroll
        for (int mt = 0; mt < 4; ++mt)
            #pragma unroll
            for (int nt = 0; nt < 4; ++nt)
                acc[mt][nt] = __builtin_amdgcn_mfma_f32_16x16x32_bf16(
                    af[mt], bf[nt], acc[mt][nt], 0, 0, 0);
    }

    #pragma unroll
    for (int nt = 0; nt < 4; ++nt) {
        const int n = n0 + wn + nt*16 + lrow;
        const float bn = bias[n];
        #pragma unroll
        for (int mt = 0; mt < 4; ++mt) {
            #pragma unroll
            for (int r = 0; r < 4; ++r) {
                const int m = m0 + wm + mt*16 + quad*4 + r;
                out[(size_t)m * 1024 + n] = acc[mt][nt][r] + bn;
            }
        }
    }
}

// ---------------------------------------------------------------------------
extern "C" void kernel_launch(void* const* d_in, const int* in_sizes, int n_in,
                              void* d_out, int out_size, void* d_ws, size_t ws_size,
                              hipStream_t stream) {
    const float* q     = (const float*)d_in[0];
    const float* k     = (const float*)d_in[1];
    const float* v     = (const float*)d_in[2];
    const float* w_in  = (const float*)d_in[3];
    const float* b_in  = (const float*)d_in[4];
    const float* w_out = (const float*)d_in[5];
    const float* b_out = (const float*)d_in[6];
    float* out = (float*)d_out;

    unsigned short* ws = (unsigned short*)d_ws;

    cast_all_kernel<<<8192, 256, 0, stream>>>(q, k, v, w_in, w_out, ws);
    qkv_gemm_kernel<<<dim3(24, 32), 256, 0, stream>>>(ws, b_in, ws);
    attn_mfma_kernel<<<dim3(16, 32), 256, 0, stream>>>(
        ws + WS_QH, ws + WS_KH, ws + WS_VT, ws + WS_ATT);
    out_gemm_kernel<<<dim3(8, 32), 256, 0, stream>>>(
        ws + WS_ATT, ws + WS_WOB, b_out, out);
}

// Round 3
// 279.455 us; speedup vs baseline: 5.1005x; 1.1526x over previous
//
#include <hip/hip_runtime.h>
#include <math.h>

#define SEQ    2048
#define BATCH  2
#define DMODEL 1024
#define NHEADS 16
#define DK     64

typedef __attribute__((ext_vector_type(8))) short  bf16x8;
typedef __attribute__((ext_vector_type(4))) float  f32x4;
typedef __attribute__((ext_vector_type(8))) unsigned short u16x8;

// async global->LDS, 16B per lane. LDS dest must be uniform_base + lane*16.
#define GLD16(gp, lp) __builtin_amdgcn_global_load_lds(                      \
    (__attribute__((address_space(1))) void*)(gp),                            \
    (__attribute__((address_space(3))) void*)(lp), 16, 0, 0)

__device__ inline unsigned short f2bf(float f) {
    unsigned int u = __float_as_uint(f);
    u += 0x7fffu + ((u >> 16) & 1u);   // round-to-nearest-even
    return (unsigned short)(u >> 16);
}

__device__ inline float fast_exp2(float x) {
#if __has_builtin(__builtin_amdgcn_exp2f)
    return __builtin_amdgcn_exp2f(x);
#else
    return __expf(x * 0.69314718055994531f);
#endif
}

// workspace layout (ushort units)
#define WS_QB   0u
#define WS_KB   4194304u
#define WS_VB   8388608u
#define WS_WIB  12582912u
#define WS_WOB  15728640u
#define WS_QH   16777216u
#define WS_KH   20971520u
#define WS_VT   25165824u
#define WS_ATT  29360128u

// ---------------------------------------------------------------------------
// Cast all f32 inputs to bf16 in workspace. 8 floats / thread.
// ---------------------------------------------------------------------------
__global__ __launch_bounds__(256) void cast_all_kernel(
    const float* __restrict__ q, const float* __restrict__ k,
    const float* __restrict__ v, const float* __restrict__ w_in,
    const float* __restrict__ w_out, unsigned short* __restrict__ ws)
{
    const int gid = blockIdx.x * 256 + threadIdx.x;   // 0..2097151
    const float* src; unsigned short* dst;
    if (gid < 524288)       { int g = gid;           src = q     + (size_t)g*8; dst = ws + WS_QB  + (size_t)g*8; }
    else if (gid < 1048576) { int g = gid - 524288;  src = k     + (size_t)g*8; dst = ws + WS_KB  + (size_t)g*8; }
    else if (gid < 1572864) { int g = gid - 1048576; src = v     + (size_t)g*8; dst = ws + WS_VB  + (size_t)g*8; }
    else if (gid < 1966080) { int g = gid - 1572864; src = w_in  + (size_t)g*8; dst = ws + WS_WIB + (size_t)g*8; }
    else                    { int g = gid - 1966080; src = w_out + (size_t)g*8; dst = ws + WS_WOB + (size_t)g*8; }
    float4 a = *(const float4*)src;
    float4 b = *(const float4*)(src + 4);
    u16x8 o;
    o[0]=f2bf(a.x); o[1]=f2bf(a.y); o[2]=f2bf(a.z); o[3]=f2bf(a.w);
    o[4]=f2bf(b.x); o[5]=f2bf(b.y); o[6]=f2bf(b.z); o[7]=f2bf(b.w);
    *(u16x8*)dst = o;
}

// ---------------------------------------------------------------------------
// QKV projection GEMM-BT (MFMA): C[m][n] = sum_k A[m][k]*W[n][k] + bias[n]
// 128x128 tile, BK=32, XOR-swizzled LDS (rows of 32 u16 = 4 chunks of 16B;
// LDS chunk c of row r holds global chunk c ^ ((r>>1)&3)).
// Q output pre-scaled by 0.125*log2(e) (softmax base-2 domain).
// V output stored transposed (bh, d, s), pair-packed 4B stores.
// ---------------------------------------------------------------------------
__global__ __launch_bounds__(256) void qkv_gemm_kernel(
    const unsigned short* __restrict__ ws_in, const float* __restrict__ bias,
    unsigned short* __restrict__ ws_out)
{
    __shared__ unsigned short As[128*32];
    __shared__ unsigned short Bs[128*32];

    const int t    = threadIdx.x;
    const int lane = t & 63;
    const int w    = t >> 6;
    const int lrow = lane & 15;
    const int quad = lane >> 4;
    const int wm   = (w >> 1) * 64;
    const int wn   = (w & 1) * 64;

    const int n0    = blockIdx.x * 128;
    const int m0    = blockIdx.y * 128;
    const int which = n0 >> 10;            // 0=q,1=k,2=v

    const unsigned short* A = ws_in + WS_QB + (size_t)which * 4194304u;
    const unsigned short* B = ws_in + WS_WIB;

    // staging: thread t fills LDS chunks t and t+256; source chunk XOR-swizzled
    const int srow = t >> 2;
    const int scc  = (t & 3) ^ ((t >> 3) & 3);
    const unsigned short* gA0 = A + (size_t)(m0 + srow) * 1024 + scc * 8;
    const unsigned short* gA1 = A + (size_t)(m0 + 64 + srow) * 1024 + scc * 8;
    const unsigned short* gB0 = B + (size_t)(n0 + srow) * 1024 + scc * 8;
    const unsigned short* gB1 = B + (size_t)(n0 + 64 + srow) * 1024 + scc * 8;

    f32x4 acc[4][4] = {};

    #pragma unroll 1
    for (int kt = 0; kt < 1024; kt += 32) {
        __syncthreads();
        GLD16(gA0, As + (size_t)t * 8);
        GLD16(gA1, As + (size_t)(t + 256) * 8);
        GLD16(gB0, Bs + (size_t)t * 8);
        GLD16(gB1, Bs + (size_t)(t + 256) * 8);
        gA0 += 32; gA1 += 32; gB0 += 32; gB1 += 32;
        __syncthreads();

        bf16x8 af[4], bf[4];
        #pragma unroll
        for (int mt = 0; mt < 4; ++mt) {
            const int r = wm + mt*16 + lrow;
            af[mt] = *(const bf16x8*)(As + r*32 + ((quad ^ ((r>>1)&3))*8));
        }
        #pragma unroll
        for (int nt = 0; nt < 4; ++nt) {
            const int r = wn + nt*16 + lrow;
            bf[nt] = *(const bf16x8*)(Bs + r*32 + ((quad ^ ((r>>1)&3))*8));
        }
        #pragma unroll
        for (int mt = 0; mt < 4; ++mt)
            #pragma unroll
            for (int nt = 0; nt < 4; ++nt)
                acc[mt][nt] = __builtin_amdgcn_mfma_f32_16x16x32_bf16(
                    af[mt], bf[nt], acc[mt][nt], 0, 0, 0);
    }

    unsigned short* dstQK = ws_out + WS_QH + (size_t)which * 4194304u;
    unsigned short* dstV  = ws_out + WS_VT;
    const float qscale = 0.18033688011112042f;   // 0.125 * log2(e)

    #pragma unroll
    for (int nt = 0; nt < 4; ++nt) {
        const int n = n0 + wn + nt*16 + lrow;
        const float bn = bias[n];
        const int h = (n & 1023) >> 6;
        const int d = n & 63;
        #pragma unroll
        for (int mt = 0; mt < 4; ++mt) {
            if (which < 2) {
                #pragma unroll
                for (int r = 0; r < 4; ++r) {
                    const int m = m0 + wm + mt*16 + quad*4 + r;
                    const int s = m >> 1, b = m & 1;
                    float val = acc[mt][nt][r] + bn;
                    if (which == 0) val *= qscale;
                    dstQK[((size_t)((b<<4) + h) * 2048 + s) * 64 + d] = f2bf(val);
                }
            } else {
                // m_base even -> b = r&1, s = s0 + (r>>1); pack (r, r+2) pairs
                const int m_base = m0 + wm + mt*16 + quad*4;
                const int s0 = m_base >> 1;
                unsigned int pk0 = (unsigned int)f2bf(acc[mt][nt][0] + bn)
                                 | ((unsigned int)f2bf(acc[mt][nt][2] + bn) << 16);
                unsigned int pk1 = (unsigned int)f2bf(acc[mt][nt][1] + bn)
                                 | ((unsigned int)f2bf(acc[mt][nt][3] + bn) << 16);
                *(unsigned int*)(dstV + ((size_t)h*64 + d)*2048 + s0)        = pk0;
                *(unsigned int*)(dstV + ((size_t)(16 + h)*64 + d)*2048 + s0) = pk1;
            }
        }
    }
}

// ---------------------------------------------------------------------------
// Flash attention. Block = (64-row Q tile, bh); 4 waves, each 16 Q rows x 64
// keys. XOR-swizzled LDS (rows of 64 u16 = 8 chunks; chunk c of row r holds
// global chunk c^(r&7)). Softmax in base-2 domain (Q pre-scaled).
// ---------------------------------------------------------------------------
__global__ __launch_bounds__(256, 4) void attn_mfma_kernel(
    const unsigned short* __restrict__ qh, const unsigned short* __restrict__ kh,
    const unsigned short* __restrict__ vt, unsigned short* __restrict__ attn)
{
    __shared__ unsigned short Qs[64*64];    // 8 KB each
    __shared__ unsigned short Ks[64*64];
    __shared__ unsigned short Vts[64*64];   // rows = d, cols = key
    __shared__ unsigned short Ps[64*64];

    const int t    = threadIdx.x;
    const int lane = t & 63;
    const int w    = t >> 6;
    const int lrow = lane & 15;
    const int quad = lane >> 4;

    const int qt = blockIdx.x;   // 0..31
    const int bh = blockIdx.y;   // 0..31

    const unsigned short* Qg = qh + ((size_t)bh * 2048 + qt * 64) * 64;
    const unsigned short* Kb = kh + (size_t)bh * 2048 * 64;
    const unsigned short* Vb = vt + (size_t)bh * 64 * 2048;

    // stage Q tile (512 chunks, swizzled source)
    #pragma unroll
    for (int i = 0; i < 2; ++i) {
        const int c = i*256 + t;
        const int row = c >> 3, cc = c & 7;
        GLD16(Qg + (size_t)row*64 + ((cc ^ (row & 7))*8), Qs + (size_t)c*8);
    }

    f32x4 O[4] = {};
    float m_i[4], l_i[4];
    #pragma unroll
    for (int r = 0; r < 4; ++r) { m_i[r] = -INFINITY; l_i[r] = 0.f; }

    #pragma unroll 1
    for (int ktile = 0; ktile < 32; ++ktile) {
        __syncthreads();
        const unsigned short* Kg = Kb + (size_t)ktile * 64 * 64;
        const unsigned short* Vg = Vb + (size_t)ktile * 64;
        #pragma unroll
        for (int i = 0; i < 2; ++i) {
            const int c = i*256 + t;
            const int row = c >> 3, cc = (c & 7) ^ (row & 7);
            GLD16(Kg + (size_t)row*64   + cc*8, Ks  + (size_t)c*8);
            GLD16(Vg + (size_t)row*2048 + cc*8, Vts + (size_t)c*8);
        }
        __syncthreads();

        // S = Q.K^T (log2-domain scores; Q pre-scaled)
        f32x4 S[4] = {};
        #pragma unroll
        for (int kk = 0; kk < 2; ++kk) {
            const int qrow = w*16 + lrow;
            bf16x8 aq = *(const bf16x8*)(Qs + qrow*64 + (((kk*4+quad) ^ (qrow&7))*8));
            #pragma unroll
            for (int nt = 0; nt < 4; ++nt) {
                const int krow = nt*16 + lrow;
                bf16x8 bk = *(const bf16x8*)(Ks + krow*64 + (((kk*4+quad) ^ (krow&7))*8));
                S[nt] = __builtin_amdgcn_mfma_f32_16x16x32_bf16(aq, bk, S[nt], 0, 0, 0);
            }
        }

        // row maxes (rows live across the 16 lanes of each quad)
        float mx[4];
        int anynew = 0;
        #pragma unroll
        for (int r = 0; r < 4; ++r) {
            float m = fmaxf(fmaxf(S[0][r], S[1][r]), fmaxf(S[2][r], S[3][r]));
            #pragma unroll
            for (int off = 1; off <= 8; off <<= 1)
                m = fmaxf(m, __shfl_xor(m, off, 64));
            mx[r] = m;
            anynew |= (m > m_i[r]);
        }

        const int prow_base = w*16 + quad*4;
        if (__any(anynew)) {
            #pragma unroll
            for (int r = 0; r < 4; ++r) {
                const float mn = fmaxf(m_i[r], mx[r]);
                const float al = fast_exp2(m_i[r] - mn);
                m_i[r] = mn;
                float rsum = 0.f;
                const int prow = prow_base + r;
                const int pb = prow * 64;
                #pragma unroll
                for (int nt = 0; nt < 4; ++nt) {
                    const float p = fast_exp2(S[nt][r] - mn);
                    const int c = nt*2 + (lrow >> 3);
                    Ps[pb + ((c ^ (prow & 7))*8) + (lrow & 7)] = f2bf(p);
                    rsum += p;
                }
                #pragma unroll
                for (int off = 1; off <= 8; off <<= 1)
                    rsum += __shfl_xor(rsum, off, 64);
                l_i[r] = l_i[r]*al + rsum;
                #pragma unroll
                for (int dt = 0; dt < 4; ++dt) O[dt][r] *= al;
            }
        } else {
            #pragma unroll
            for (int r = 0; r < 4; ++r) {
                const float mn = m_i[r];
                float rsum = 0.f;
                const int prow = prow_base + r;
                const int pb = prow * 64;
                #pragma unroll
                for (int nt = 0; nt < 4; ++nt) {
                    const float p = fast_exp2(S[nt][r] - mn);
                    const int c = nt*2 + (lrow >> 3);
                    Ps[pb + ((c ^ (prow & 7))*8) + (lrow & 7)] = f2bf(p);
                    rsum += p;
                }
                #pragma unroll
                for (int off = 1; off <= 8; off <<= 1)
                    rsum += __shfl_xor(rsum, off, 64);
                l_i[r] += rsum;
            }
        }

        // O += P.V
        #pragma unroll
        for (int kk = 0; kk < 2; ++kk) {
            const int prow = w*16 + lrow;
            bf16x8 ap = *(const bf16x8*)(Ps + prow*64 + (((kk*4+quad) ^ (prow&7))*8));
            #pragma unroll
            for (int dt = 0; dt < 4; ++dt) {
                const int vrow = dt*16 + lrow;
                bf16x8 bv = *(const bf16x8*)(Vts + vrow*64 + (((kk*4+quad) ^ (vrow&7))*8));
                O[dt] = __builtin_amdgcn_mfma_f32_16x16x32_bf16(ap, bv, O[dt], 0, 0, 0);
            }
        }
    }

    // epilogue: attn row = s*B + b, col = h*64 + d (bf16)
    const int b_ = bh >> 4, h_ = bh & 15;
    #pragma unroll
    for (int r = 0; r < 4; ++r) {
        const float inv = 1.f / l_i[r];
        const int s_ = qt*64 + w*16 + quad*4 + r;
        #pragma unroll
        for (int dt = 0; dt < 4; ++dt) {
            attn[((size_t)(s_*2 + b_)) * 1024 + h_*64 + dt*16 + lrow] =
                f2bf(O[dt][r] * inv);
        }
    }
}

// ---------------------------------------------------------------------------
// Out projection GEMM-BT (MFMA): 64x128 tile (512 blocks for occupancy).
// ---------------------------------------------------------------------------
__global__ __launch_bounds__(256) void out_gemm_kernel(
    const unsigned short* __restrict__ A, const unsigned short* __restrict__ B,
    const float* __restrict__ bias, float* __restrict__ out)
{
    __shared__ unsigned short As[64*32];
    __shared__ unsigned short Bs[128*32];

    const int t    = threadIdx.x;
    const int lane = t & 63;
    const int w    = t >> 6;
    const int lrow = lane & 15;
    const int quad = lane >> 4;
    const int wn   = (w >> 1) * 64;
    const int wm   = (w & 1) * 32;

    const int n0 = blockIdx.x * 128;
    const int m0 = blockIdx.y * 64;

    const int srow = t >> 2;
    const int scc  = (t & 3) ^ ((t >> 3) & 3);
    const unsigned short* gA0 = A + (size_t)(m0 + srow) * 1024 + scc * 8;
    const unsigned short* gB0 = B + (size_t)(n0 + srow) * 1024 + scc * 8;
    const unsigned short* gB1 = B + (size_t)(n0 + 64 + srow) * 1024 + scc * 8;

    f32x4 acc[2][4] = {};

    #pragma unroll 1
    for (int kt = 0; kt < 1024; kt += 32) {
        __syncthreads();
        GLD16(gA0, As + (size_t)t * 8);
        GLD16(gB0, Bs + (size_t)t * 8);
        GLD16(gB1, Bs + (size_t)(t + 256) * 8);
        gA0 += 32; gB0 += 32; gB1 += 32;
        __syncthreads();

        bf16x8 af[2], bf[4];
        #pragma unroll
        for (int mt = 0; mt < 2; ++mt) {
            const int r = wm + mt*16 + lrow;
            af[mt] = *(const bf16x8*)(As + r*32 + ((quad ^ ((r>>1)&3))*8));
        }
        #pragma unroll
        for (int nt = 0; nt < 4; ++nt) {
            const int r = wn + nt*16 + lrow;
            bf[nt] = *(const bf16x8*)(Bs + r*32 + ((quad ^ ((r>>1)&3))*8));
        }
        #pragma unroll
        for (int mt = 0; mt < 2; ++mt)
            #pragma unroll
            for (int nt = 0; nt < 4; ++nt)
                acc[mt][nt] = __builtin_amdgcn_mfma_f32_16x16x32_bf16(
                    af[mt], bf[nt], acc[mt][nt], 0, 0, 0);
    }

    #pragma unroll
    for (int nt = 0; nt < 4; ++nt) {
        const int n = n0 + wn + nt*16 + lrow;
        const float bn = bias[n];
        #pragma unroll
        for (int mt = 0; mt < 2; ++mt) {
            #pragma unroll
            for (int r = 0; r < 4; ++r) {
                const int m = m0 + wm + mt*16 + quad*4 + r;
                out[(size_t)m * 1024 + n] = acc[mt][nt][r] + bn;
            }
        }
    }
}

// ---------------------------------------------------------------------------
extern "C" void kernel_launch(void* const* d_in, const int* in_sizes, int n_in,
                              void* d_out, int out_size, void* d_ws, size_t ws_size,
                              hipStream_t stream) {
    const float* q     = (const float*)d_in[0];
    const float* k     = (const float*)d_in[1];
    const float* v     = (const float*)d_in[2];
    const float* w_in  = (const float*)d_in[3];
    const float* b_in  = (const float*)d_in[4];
    const float* w_out = (const float*)d_in[5];
    const float* b_out = (const float*)d_in[6];
    float* out = (float*)d_out;

    unsigned short* ws = (unsigned short*)d_ws;

    cast_all_kernel<<<8192, 256, 0, stream>>>(q, k, v, w_in, w_out, ws);
    qkv_gemm_kernel<<<dim3(24, 32), 256, 0, stream>>>(ws, b_in, ws);
    attn_mfma_kernel<<<dim3(32, 32), 256, 0, stream>>>(
        ws + WS_QH, ws + WS_KH, ws + WS_VT, ws + WS_ATT);
    out_gemm_kernel<<<dim3(8, 64), 256, 0, stream>>>(
        ws + WS_ATT, ws + WS_WOB, b_out, out);
}

// Round 4
// 252.363 us; speedup vs baseline: 5.6481x; 1.1074x over previous
//
#include <hip/hip_runtime.h>
#include <math.h>

#define SEQ    2048
#define BATCH  2
#define DMODEL 1024
#define NHEADS 16
#define DK     64

typedef __attribute__((ext_vector_type(8))) short  bf16x8;
typedef __attribute__((ext_vector_type(4))) float  f32x4;
typedef __attribute__((ext_vector_type(8))) unsigned short u16x8;

// async global->LDS, 16B per lane. LDS dest must be uniform_base + lane*16.
#define GLD16(gp, lp) __builtin_amdgcn_global_load_lds(                      \
    (__attribute__((address_space(1))) void*)(gp),                            \
    (__attribute__((address_space(3))) void*)(lp), 16, 0, 0)

__device__ inline unsigned short f2bf(float f) {
    unsigned int u = __float_as_uint(f);
    u += 0x7fffu + ((u >> 16) & 1u);   // round-to-nearest-even
    return (unsigned short)(u >> 16);
}

// pack two f32 -> two bf16 in one u32 (v_cvt_pk_bf16_f32 on gfx950)
__device__ inline unsigned int pk2bf(float a, float b) {
#if __has_builtin(__builtin_amdgcn_cvt_pk_bf16_f32)
    typedef __attribute__((ext_vector_type(2))) __bf16 v2bf;
    v2bf r = __builtin_amdgcn_cvt_pk_bf16_f32(a, b);
    unsigned int u; __builtin_memcpy(&u, &r, 4); return u;
#else
    return (unsigned int)f2bf(a) | ((unsigned int)f2bf(b) << 16);
#endif
}

__device__ inline float fast_exp2(float x) {
#if __has_builtin(__builtin_amdgcn_exp2f)
    return __builtin_amdgcn_exp2f(x);
#else
    return __expf(x * 0.69314718055994531f);
#endif
}

// workspace layout (ushort units)
#define WS_QB   0u
#define WS_KB   4194304u
#define WS_VB   8388608u
#define WS_WIB  12582912u
#define WS_WOB  15728640u
#define WS_QH   16777216u
#define WS_KH   20971520u
#define WS_VT   25165824u
#define WS_ATT  29360128u

// ---------------------------------------------------------------------------
// Cast all f32 inputs to bf16 in workspace. 8 floats / thread.
// ---------------------------------------------------------------------------
__global__ __launch_bounds__(256) void cast_all_kernel(
    const float* __restrict__ q, const float* __restrict__ k,
    const float* __restrict__ v, const float* __restrict__ w_in,
    const float* __restrict__ w_out, unsigned short* __restrict__ ws)
{
    const int gid = blockIdx.x * 256 + threadIdx.x;   // 0..2097151
    const float* src; unsigned short* dst;
    if (gid < 524288)       { int g = gid;           src = q     + (size_t)g*8; dst = ws + WS_QB  + (size_t)g*8; }
    else if (gid < 1048576) { int g = gid - 524288;  src = k     + (size_t)g*8; dst = ws + WS_KB  + (size_t)g*8; }
    else if (gid < 1572864) { int g = gid - 1048576; src = v     + (size_t)g*8; dst = ws + WS_VB  + (size_t)g*8; }
    else if (gid < 1966080) { int g = gid - 1572864; src = w_in  + (size_t)g*8; dst = ws + WS_WIB + (size_t)g*8; }
    else                    { int g = gid - 1966080; src = w_out + (size_t)g*8; dst = ws + WS_WOB + (size_t)g*8; }
    float4 a = *(const float4*)src;
    float4 b = *(const float4*)(src + 4);
    u16x8 o;
    o[0]=f2bf(a.x); o[1]=f2bf(a.y); o[2]=f2bf(a.z); o[3]=f2bf(a.w);
    o[4]=f2bf(b.x); o[5]=f2bf(b.y); o[6]=f2bf(b.z); o[7]=f2bf(b.w);
    *(u16x8*)dst = o;
}

// ---------------------------------------------------------------------------
// QKV projection GEMM-BT (MFMA): C[m][n] = sum_k A[m][k]*W[n][k] + bias[n]
// 128x128 tile, BK=32, XOR-swizzled LDS.
// Q output pre-scaled by 0.125*log2(e) (softmax base-2 domain).
// V output stored transposed (bh, d, s), pair-packed 4B stores.
// ---------------------------------------------------------------------------
__global__ __launch_bounds__(256) void qkv_gemm_kernel(
    const unsigned short* __restrict__ ws_in, const float* __restrict__ bias,
    unsigned short* __restrict__ ws_out)
{
    __shared__ unsigned short As[128*32];
    __shared__ unsigned short Bs[128*32];

    const int t    = threadIdx.x;
    const int lane = t & 63;
    const int w    = t >> 6;
    const int lrow = lane & 15;
    const int quad = lane >> 4;
    const int wm   = (w >> 1) * 64;
    const int wn   = (w & 1) * 64;

    const int n0    = blockIdx.x * 128;
    const int m0    = blockIdx.y * 128;
    const int which = n0 >> 10;            // 0=q,1=k,2=v

    const unsigned short* A = ws_in + WS_QB + (size_t)which * 4194304u;
    const unsigned short* B = ws_in + WS_WIB;

    const int srow = t >> 2;
    const int scc  = (t & 3) ^ ((t >> 3) & 3);
    const unsigned short* gA0 = A + (size_t)(m0 + srow) * 1024 + scc * 8;
    const unsigned short* gA1 = A + (size_t)(m0 + 64 + srow) * 1024 + scc * 8;
    const unsigned short* gB0 = B + (size_t)(n0 + srow) * 1024 + scc * 8;
    const unsigned short* gB1 = B + (size_t)(n0 + 64 + srow) * 1024 + scc * 8;

    f32x4 acc[4][4] = {};

    #pragma unroll 1
    for (int kt = 0; kt < 1024; kt += 32) {
        __syncthreads();
        GLD16(gA0, As + (size_t)t * 8);
        GLD16(gA1, As + (size_t)(t + 256) * 8);
        GLD16(gB0, Bs + (size_t)t * 8);
        GLD16(gB1, Bs + (size_t)(t + 256) * 8);
        gA0 += 32; gA1 += 32; gB0 += 32; gB1 += 32;
        __syncthreads();

        bf16x8 af[4], bf[4];
        #pragma unroll
        for (int mt = 0; mt < 4; ++mt) {
            const int r = wm + mt*16 + lrow;
            af[mt] = *(const bf16x8*)(As + r*32 + ((quad ^ ((r>>1)&3))*8));
        }
        #pragma unroll
        for (int nt = 0; nt < 4; ++nt) {
            const int r = wn + nt*16 + lrow;
            bf[nt] = *(const bf16x8*)(Bs + r*32 + ((quad ^ ((r>>1)&3))*8));
        }
        #pragma unroll
        for (int mt = 0; mt < 4; ++mt)
            #pragma unroll
            for (int nt = 0; nt < 4; ++nt)
                acc[mt][nt] = __builtin_amdgcn_mfma_f32_16x16x32_bf16(
                    af[mt], bf[nt], acc[mt][nt], 0, 0, 0);
    }

    unsigned short* dstQK = ws_out + WS_QH + (size_t)which * 4194304u;
    unsigned short* dstV  = ws_out + WS_VT;
    const float qscale = 0.18033688011112042f;   // 0.125 * log2(e)

    #pragma unroll
    for (int nt = 0; nt < 4; ++nt) {
        const int n = n0 + wn + nt*16 + lrow;
        const float bn = bias[n];
        const int h = (n & 1023) >> 6;
        const int d = n & 63;
        #pragma unroll
        for (int mt = 0; mt < 4; ++mt) {
            if (which < 2) {
                #pragma unroll
                for (int r = 0; r < 4; ++r) {
                    const int m = m0 + wm + mt*16 + quad*4 + r;
                    const int s = m >> 1, b = m & 1;
                    float val = acc[mt][nt][r] + bn;
                    if (which == 0) val *= qscale;
                    dstQK[((size_t)((b<<4) + h) * 2048 + s) * 64 + d] = f2bf(val);
                }
            } else {
                const int m_base = m0 + wm + mt*16 + quad*4;
                const int s0 = m_base >> 1;
                unsigned int pk0 = pk2bf(acc[mt][nt][0] + bn, acc[mt][nt][2] + bn);
                unsigned int pk1 = pk2bf(acc[mt][nt][1] + bn, acc[mt][nt][3] + bn);
                *(unsigned int*)(dstV + ((size_t)h*64 + d)*2048 + s0)        = pk0;
                *(unsigned int*)(dstV + ((size_t)(16 + h)*64 + d)*2048 + s0) = pk1;
            }
        }
    }
}

// ---------------------------------------------------------------------------
// Flash attention, transposed-score form. Block = (64-query tile, bh),
// 128 threads = 2 waves; wave owns 32 queries (2 N-tiles).
// S^T = K.Q^T  (C-layout: col=query=lane&15 -> key-reduction is 15 in-reg
// ops + 2 shfl).  O^T = V.P^T accumulated in the same query=col domain, so
// softmax stats / alpha rescale / epilogue need no cross-lane transposes.
// P round-trips through LDS as packed b64 stores. All LDS XOR-swizzled.
// ---------------------------------------------------------------------------
__global__ __launch_bounds__(128) void attn_mfma_kernel(
    const unsigned short* __restrict__ qh, const unsigned short* __restrict__ kh,
    const unsigned short* __restrict__ vt, unsigned short* __restrict__ attn)
{
    __shared__ unsigned short Qs[64*64];    // 8 KB each
    __shared__ unsigned short Ks[64*64];
    __shared__ unsigned short Vts[64*64];   // rows = d, cols = key
    __shared__ unsigned short Ps[64*64];    // rows = query, cols = key

    const int t    = threadIdx.x;           // 0..127
    const int lane = t & 63;
    const int w    = t >> 6;                // 0..1
    const int lrow = lane & 15;
    const int quad = lane >> 4;

    const int qt = blockIdx.x;   // 0..31
    const int bh = blockIdx.y;   // 0..31

    const unsigned short* Qg = qh + ((size_t)bh * 2048 + qt * 64) * 64;
    const unsigned short* Kb = kh + (size_t)bh * 2048 * 64;
    const unsigned short* Vb = vt + (size_t)bh * 64 * 2048;

    // stage Q tile (512 chunks of 16B, 4 per thread, swizzled source)
    #pragma unroll
    for (int i = 0; i < 4; ++i) {
        const int c = i*128 + t;
        const int row = c >> 3, cc = (c & 7) ^ (row & 7);
        GLD16(Qg + (size_t)row*64 + cc*8, Qs + (size_t)c*8);
    }

    f32x4 O[4][2] = {};          // [d-tile][query-tile], col=query
    float m_i[2] = {-INFINITY, -INFINITY}, l_i[2] = {0.f, 0.f};

    #pragma unroll 1
    for (int ktile = 0; ktile < 32; ++ktile) {
        __syncthreads();
        const unsigned short* Kg = Kb + (size_t)ktile * 64 * 64;
        const unsigned short* Vg = Vb + (size_t)ktile * 64;
        #pragma unroll
        for (int i = 0; i < 4; ++i) {
            const int c = i*128 + t;
            const int row = c >> 3, cc = (c & 7) ^ (row & 7);
            GLD16(Kg + (size_t)row*64   + cc*8, Ks  + (size_t)c*8);
            GLD16(Vg + (size_t)row*2048 + cc*8, Vts + (size_t)c*8);
        }
        __syncthreads();

        // S^T = K.Q^T : ST[m][n], rows=keys (m*16+quad*4+r), cols=queries
        f32x4 ST[4][2] = {};
        #pragma unroll
        for (int kk = 0; kk < 2; ++kk) {
            bf16x8 kf[4], qf[2];
            #pragma unroll
            for (int m = 0; m < 4; ++m) {
                const int r = m*16 + lrow;
                kf[m] = *(const bf16x8*)(Ks + r*64 + (((kk*4+quad) ^ (r&7))*8));
            }
            #pragma unroll
            for (int n = 0; n < 2; ++n) {
                const int r = w*32 + n*16 + lrow;
                qf[n] = *(const bf16x8*)(Qs + r*64 + (((kk*4+quad) ^ (r&7))*8));
            }
            #pragma unroll
            for (int m = 0; m < 4; ++m)
                #pragma unroll
                for (int n = 0; n < 2; ++n)
                    ST[m][n] = __builtin_amdgcn_mfma_f32_16x16x32_bf16(
                        kf[m], qf[n], ST[m][n], 0, 0, 0);
        }

        // key-max per query (15 in-register max + 2 shfl)
        float mx[2], al[2];
        int anynew = 0;
        #pragma unroll
        for (int n = 0; n < 2; ++n) {
            float mm;
            #pragma unroll
            for (int m = 0; m < 4; ++m) {
                float m01 = fmaxf(fmaxf(ST[m][n][0], ST[m][n][1]),
                                  fmaxf(ST[m][n][2], ST[m][n][3]));
                mm = (m == 0) ? m01 : fmaxf(mm, m01);
            }
            mm = fmaxf(mm, __shfl_xor(mm, 16, 64));
            mm = fmaxf(mm, __shfl_xor(mm, 32, 64));
            mx[n] = mm;
            anynew |= (mm > m_i[n]);
        }

        if (__any(anynew)) {
            #pragma unroll
            for (int n = 0; n < 2; ++n) {
                const float mn = fmaxf(m_i[n], mx[n]);
                al[n] = fast_exp2(m_i[n] - mn);
                m_i[n] = mn;
            }
            #pragma unroll
            for (int dt = 0; dt < 4; ++dt)
                #pragma unroll
                for (int n = 0; n < 2; ++n)
                    O[dt][n] *= al[n];
        } else {
            al[0] = 1.f; al[1] = 1.f;
        }

        // P = exp2(S - m), packed b64 stores to Ps[query][key]; row sums
        #pragma unroll
        for (int n = 0; n < 2; ++n) {
            const int prow = w*32 + n*16 + lrow;
            const float mn = m_i[n];
            float rsum = 0.f;
            #pragma unroll
            for (int m = 0; m < 4; ++m) {
                const float p0 = fast_exp2(ST[m][n][0] - mn);
                const float p1 = fast_exp2(ST[m][n][1] - mn);
                const float p2 = fast_exp2(ST[m][n][2] - mn);
                const float p3 = fast_exp2(ST[m][n][3] - mn);
                rsum += (p0 + p1) + (p2 + p3);
                uint2 pk;
                pk.x = pk2bf(p0, p1);
                pk.y = pk2bf(p2, p3);
                const int sc = (m*2 + (quad >> 1)) ^ (prow & 7);
                *(uint2*)(Ps + prow*64 + sc*8 + (quad & 1)*4) = pk;
            }
            rsum += __shfl_xor(rsum, 16, 64);
            rsum += __shfl_xor(rsum, 32, 64);
            l_i[n] = l_i[n]*al[n] + rsum;
        }

        // O^T += V.P^T  (A = V^T-frag rows=d, B = P-frag cols=query)
        #pragma unroll
        for (int kk = 0; kk < 2; ++kk) {
            bf16x8 vf[4], pf[2];
            #pragma unroll
            for (int dt = 0; dt < 4; ++dt) {
                const int r = dt*16 + lrow;
                vf[dt] = *(const bf16x8*)(Vts + r*64 + (((kk*4+quad) ^ (r&7))*8));
            }
            #pragma unroll
            for (int n = 0; n < 2; ++n) {
                const int r = w*32 + n*16 + lrow;
                pf[n] = *(const bf16x8*)(Ps + r*64 + (((kk*4+quad) ^ (r&7))*8));
            }
            #pragma unroll
            for (int dt = 0; dt < 4; ++dt)
                #pragma unroll
                for (int n = 0; n < 2; ++n)
                    O[dt][n] = __builtin_amdgcn_mfma_f32_16x16x32_bf16(
                        vf[dt], pf[n], O[dt][n], 0, 0, 0);
        }
    }

    // epilogue: O^T lane layout: d = dt*16+quad*4+r, query = w*32+n*16+lrow
    const int b_ = bh >> 4, h_ = bh & 15;
    #pragma unroll
    for (int n = 0; n < 2; ++n) {
        const float inv = 1.f / l_i[n];
        const int s_ = qt*64 + w*32 + n*16 + lrow;
        unsigned short* dst = attn + ((size_t)(s_*2 + b_)) * 1024 + h_*64;
        #pragma unroll
        for (int dt = 0; dt < 4; ++dt) {
            uint2 pk;
            pk.x = pk2bf(O[dt][n][0]*inv, O[dt][n][1]*inv);
            pk.y = pk2bf(O[dt][n][2]*inv, O[dt][n][3]*inv);
            *(uint2*)(dst + dt*16 + quad*4) = pk;
        }
    }
}

// ---------------------------------------------------------------------------
// Out projection GEMM-BT (MFMA): 64x128 tile (512 blocks for occupancy).
// ---------------------------------------------------------------------------
__global__ __launch_bounds__(256) void out_gemm_kernel(
    const unsigned short* __restrict__ A, const unsigned short* __restrict__ B,
    const float* __restrict__ bias, float* __restrict__ out)
{
    __shared__ unsigned short As[64*32];
    __shared__ unsigned short Bs[128*32];

    const int t    = threadIdx.x;
    const int lane = t & 63;
    const int w    = t >> 6;
    const int lrow = lane & 15;
    const int quad = lane >> 4;
    const int wn   = (w >> 1) * 64;
    const int wm   = (w & 1) * 32;

    const int n0 = blockIdx.x * 128;
    const int m0 = blockIdx.y * 64;

    const int srow = t >> 2;
    const int scc  = (t & 3) ^ ((t >> 3) & 3);
    const unsigned short* gA0 = A + (size_t)(m0 + srow) * 1024 + scc * 8;
    const unsigned short* gB0 = B + (size_t)(n0 + srow) * 1024 + scc * 8;
    const unsigned short* gB1 = B + (size_t)(n0 + 64 + srow) * 1024 + scc * 8;

    f32x4 acc[2][4] = {};

    #pragma unroll 1
    for (int kt = 0; kt < 1024; kt += 32) {
        __syncthreads();
        GLD16(gA0, As + (size_t)t * 8);
        GLD16(gB0, Bs + (size_t)t * 8);
        GLD16(gB1, Bs + (size_t)(t + 256) * 8);
        gA0 += 32; gB0 += 32; gB1 += 32;
        __syncthreads();

        bf16x8 af[2], bf[4];
        #pragma unroll
        for (int mt = 0; mt < 2; ++mt) {
            const int r = wm + mt*16 + lrow;
            af[mt] = *(const bf16x8*)(As + r*32 + ((quad ^ ((r>>1)&3))*8));
        }
        #pragma unroll
        for (int nt = 0; nt < 4; ++nt) {
            const int r = wn + nt*16 + lrow;
            bf[nt] = *(const bf16x8*)(Bs + r*32 + ((quad ^ ((r>>1)&3))*8));
        }
        #pragma unroll
        for (int mt = 0; mt < 2; ++mt)
            #pragma unroll
            for (int nt = 0; nt < 4; ++nt)
                acc[mt][nt] = __builtin_amdgcn_mfma_f32_16x16x32_bf16(
                    af[mt], bf[nt], acc[mt][nt], 0, 0, 0);
    }

    #pragma unroll
    for (int nt = 0; nt < 4; ++nt) {
        const int n = n0 + wn + nt*16 + lrow;
        const float bn = bias[n];
        #pragma unroll
        for (int mt = 0; mt < 2; ++mt) {
            #pragma unroll
            for (int r = 0; r < 4; ++r) {
                const int m = m0 + wm + mt*16 + quad*4 + r;
                out[(size_t)m * 1024 + n] = acc[mt][nt][r] + bn;
            }
        }
    }
}

// ---------------------------------------------------------------------------
extern "C" void kernel_launch(void* const* d_in, const int* in_sizes, int n_in,
                              void* d_out, int out_size, void* d_ws, size_t ws_size,
                              hipStream_t stream) {
    const float* q     = (const float*)d_in[0];
    const float* k     = (const float*)d_in[1];
    const float* v     = (const float*)d_in[2];
    const float* w_in  = (const float*)d_in[3];
    const float* b_in  = (const float*)d_in[4];
    const float* w_out = (const float*)d_in[5];
    const float* b_out = (const float*)d_in[6];
    float* out = (float*)d_out;

    unsigned short* ws = (unsigned short*)d_ws;

    cast_all_kernel<<<8192, 256, 0, stream>>>(q, k, v, w_in, w_out, ws);
    qkv_gemm_kernel<<<dim3(24, 32), 256, 0, stream>>>(ws, b_in, ws);
    attn_mfma_kernel<<<dim3(32, 32), 128, 0, stream>>>(
        ws + WS_QH, ws + WS_KH, ws + WS_VT, ws + WS_ATT);
    out_gemm_kernel<<<dim3(8, 64), 256, 0, stream>>>(
        ws + WS_ATT, ws + WS_WOB, b_out, out);
}